// Round 5
// baseline (606.440 us; speedup 1.0000x reference)
//
#include <hip/hip_runtime.h>

#define N_ROWS 100000
#define M_NBR  12
#define C_DIM  64
#define F_DIM  41
#define E_TOT  (N_ROWS * M_NBR)

// ---------------------------------------------------------------------------
// Kernel A: s_e = (softplus(x_e @ W1 + b1) . w2[:,0] + b2[0]) * c
// No LDS, no launch_bounds min-waves (R4's ",7" caused h[41] to spill:
// VGPR 36 + 170 MB scratch writes). Each thread streams its own 164 B row
// directly from global (4-float register double-buffer), weights via
// wave-uniform s_load. VGPR ~60 -> 8 waves/SIMD; zero LDS -> occupancy
// bounded only by VGPRs.
// ---------------------------------------------------------------------------
__global__ __launch_bounds__(256) void edge_mlp_kernel(
    const float* __restrict__ nbr_fea,   // [E, F]
    const float* __restrict__ w1,        // [F, F]
    const float* __restrict__ b1,        // [F]
    const float* __restrict__ w2,        // [F, 9]
    const float* __restrict__ b2,        // [9]
    float* __restrict__ s_out)           // [E]
{
    const long e = (long)blockIdx.x * 256 + threadIdx.x;
    if (e >= (long)E_TOT) return;        // tail block only; no syncthreads in kernel

    const float* __restrict__ xr = nbr_fea + e * F_DIM;

    float h[F_DIM];
    #pragma unroll
    for (int j = 0; j < F_DIM; ++j) h[j] = b1[j];   // s_load (uniform)

    // register double-buffer of 4 x-values; prefetch next group before compute
    float xc[4];
    #pragma unroll
    for (int u = 0; u < 4; ++u) xc[u] = xr[u];

    #pragma unroll 1
    for (int k0 = 0; k0 < 40; k0 += 4) {
        float xn[4];
        #pragma unroll
        for (int u = 0; u < 4; ++u) {
            int kn = k0 + 4 + u;
            xn[u] = xr[kn < F_DIM ? kn : (F_DIM - 1)];   // clamp keeps addr in-bounds
        }
        #pragma unroll
        for (int u = 0; u < 4; ++u) {
            const float* wr = w1 + (k0 + u) * F_DIM;     // uniform -> s_load
            float xk = xc[u];
            #pragma unroll
            for (int j = 0; j < F_DIM; ++j) h[j] = fmaf(xk, wr[j], h[j]);
        }
        #pragma unroll
        for (int u = 0; u < 4; ++u) xc[u] = xn[u];
    }
    {   // tail k = 40 (value sits in xc[0] after the last rotate)
        const float* wr = w1 + 40 * F_DIM;
        float xk = xc[0];
        #pragma unroll
        for (int j = 0; j < F_DIM; ++j) h[j] = fmaf(xk, wr[j], h[j]);
    }

    // epilogue: softplus + dot with w2[:,0]
    float acc = b2[0];
    #pragma unroll
    for (int j = 0; j < F_DIM; ++j) {
        float v = h[j];
        float sp = fmaxf(v, 0.0f) + __logf(1.0f + __expf(-fabsf(v)));
        acc = fmaf(sp, w2[j * 9], acc);              // w2 col 0, s_load
    }
    s_out[e] = acc * (0.28209479177387814f / 12.0f);
}

// ---------------------------------------------------------------------------
// Kernel B (fused): acc_r = sum_j s_rj * atom_fea[idx_rj][:] (lane = channel,
// coalesced 256B row gathers), then out_r = acc_r @ (tp_w/8) via v_readlane
// outer-product on the VALU pipe (no LDS broadcast, no afT round-trip).
// Unchanged from R3/R4 (passed, absmax 4.9e-4).
// ---------------------------------------------------------------------------
__global__ __launch_bounds__(256) void gather_transform_kernel(
    const float* __restrict__ atom_fea,  // [N, C]
    const int*   __restrict__ nbr_idx,   // [N, M]
    const float* __restrict__ s,         // [E]
    const float* __restrict__ tp_w,      // [C, C]
    float* __restrict__ out)             // [N, C]
{
    __shared__ int   lidx[64 * M_NBR];
    __shared__ float lsv [64 * M_NBR];

    const int tid  = threadIdx.x;
    const int lane = tid & 63;
    const int wv   = tid >> 6;
    const int row0 = blockIdx.x * 64;

    const long ebase = (long)row0 * M_NBR;
    for (int i = tid; i < 64 * M_NBR; i += 256) {
        long g = ebase + i;
        bool ok = g < (long)E_TOT;
        lidx[i] = ok ? nbr_idx[g] : 0;
        lsv[i]  = ok ? s[g]       : 0.0f;
    }

    float Tc[64];
    #pragma unroll
    for (int k = 0; k < 64; ++k) Tc[k] = tp_w[k * 64 + lane] * 0.125f;
    __syncthreads();

    float acc[16];
    #pragma unroll
    for (int i = 0; i < 16; ++i) acc[i] = 0.0f;

    #pragma unroll 4
    for (int i = 0; i < 16; ++i) {
        const int rl = wv * 16 + i;
        #pragma unroll
        for (int j = 0; j < M_NBR; ++j) {
            int   idx = lidx[rl * M_NBR + j];   // LDS broadcast
            float sv  = lsv [rl * M_NBR + j];
            acc[i] = fmaf(sv, atom_fea[(long)idx * C_DIM + lane], acc[i]);
        }
    }

    #pragma unroll
    for (int i = 0; i < 16; ++i) {
        int r = row0 + wv * 16 + i;
        if (r < N_ROWS) {                       // wave-uniform guard
            float o = 0.0f;
            #pragma unroll
            for (int k = 0; k < 64; ++k) {
                float a = __int_as_float(__builtin_amdgcn_readlane(__float_as_int(acc[i]), k));
                o = fmaf(a, Tc[k], o);
            }
            out[(long)r * C_DIM + lane] = o;    // coalesced
        }
    }
}

extern "C" void kernel_launch(void* const* d_in, const int* in_sizes, int n_in,
                              void* d_out, int out_size, void* d_ws, size_t ws_size,
                              hipStream_t stream) {
    const float* atom_fea = (const float*)d_in[0];
    const float* nbr_fea  = (const float*)d_in[1];
    const int*   nbr_idx  = (const int*)  d_in[2];
    // d_in[3] = pos : dead (only the constant l=0 SH channel couples)
    const float* w1   = (const float*)d_in[4];
    const float* b1   = (const float*)d_in[5];
    const float* w2   = (const float*)d_in[6];
    const float* b2   = (const float*)d_in[7];
    const float* tp_w = (const float*)d_in[8];

    float* s   = (float*)d_ws;                   // 4.8 MB scratch
    float* out = (float*)d_out;

    const int blocksA = (E_TOT + 255) / 256;     // 4688
    edge_mlp_kernel<<<blocksA, 256, 0, stream>>>(nbr_fea, w1, b1, w2, b2, s);

    const int blocksB = (N_ROWS + 63) / 64;      // 1563
    gather_transform_kernel<<<blocksB, 256, 0, stream>>>(atom_fea, nbr_idx, s, tp_w, out);
}